// Round 6
// baseline (96.689 us; speedup 1.0000x reference)
//
#include <hip/hip_runtime.h>
#include <math.h>

#define LL 768
#define CT 64
#define KD 192
#define OC 1024
#define PCH 68           // partial line: 64 ch + z at [64]
#define NJS 12           // 768/64 col strips
#define NIS 96           // 768/8 row strips

// 16-lane-group sum via DPP (xor1, xor2, ror4, ror8) — pure VALU, no DS.
__device__ __forceinline__ float row16_sum(float x) {
    x += __int_as_float(__builtin_amdgcn_update_dpp(0, __float_as_int(x), 0xB1, 0xF, 0xF, true));
    x += __int_as_float(__builtin_amdgcn_update_dpp(0, __float_as_int(x), 0x4E, 0xF, 0xF, true));
    x += __int_as_float(__builtin_amdgcn_update_dpp(0, __float_as_int(x), 0x124, 0xF, 0xF, true));
    x += __int_as_float(__builtin_amdgcn_update_dpp(0, __float_as_int(x), 0x128, 0xF, 0xF, true));
    return x;
}

// ---------------- K1: fused logits+exp+row/col sums, 1 feat pass ----------------
// tile = 8 rows x 64 cols -> per i-iter the block reads 16KB CONTIGUOUS.
// thread: u=t>>4 (col-in-substrip), q=t&15 (channel quad), w=t>>6.
// cols covered by thread: j0 + jj*16 + u for jj=0..3 (col partials in regs).
// row partials: accumulate e*f over jj in regs, one shfl16/32 reduce + one
// LDS RMW per (wave,i); cross-wave fold at tile end.
__global__ __launch_bounds__(256) void k_fused(const float* __restrict__ feat,
                                               const float* __restrict__ Wq,
                                               const float* __restrict__ bq,
                                               float* __restrict__ rp,
                                               float* __restrict__ cp) {
    __shared__ float rpart[4][8][72];

    int t = threadIdx.x;
    int u = t >> 4, q = t & 15, w = t >> 6;

    // bijective XCD swizzle: 1152 = 8 * 144
    int bid = blockIdx.x;
    int nb = (bid & 7) * 144 + (bid >> 3);
    int bi = nb / NJS, bj = nb % NJS;
    int i0 = bi * 8, j0 = bj * 64;

    const float4 wq = *reinterpret_cast<const float4*>(Wq + q * 4);
    const float bqv = bq[0];

    // zero rpart (4*8*72 = 2304 floats)
    {
        float* rz = &rpart[0][0][0];
        #pragma unroll
        for (int x = 0; x < 9; ++x) rz[t + x * 256] = 0.f;
    }
    __syncthreads();

    const size_t istr = (size_t)LL * CT;
    const float* fb = feat + ((size_t)i0 * LL + j0 + u) * CT + q * 4;

    float4 cr0 = make_float4(0,0,0,0), cr1 = make_float4(0,0,0,0);
    float4 cr2 = make_float4(0,0,0,0), cr3 = make_float4(0,0,0,0);
    float zc0 = 0.f, zc1 = 0.f, zc2 = 0.f, zc3 = 0.f;

    #define STEP(F, CR, ZC)                                              \
        {                                                                \
            float s = F.x * wq.x + F.y * wq.y + F.z * wq.z + F.w * wq.w; \
            s = row16_sum(s);                                            \
            float e = __expf(s + bqv);                                   \
            CR.x = fmaf(e, F.x, CR.x);                                   \
            CR.y = fmaf(e, F.y, CR.y);                                   \
            CR.z = fmaf(e, F.z, CR.z);                                   \
            CR.w = fmaf(e, F.w, CR.w);                                   \
            ZC += e;                                                     \
            pr.x = fmaf(e, F.x, pr.x);                                   \
            pr.y = fmaf(e, F.y, pr.y);                                   \
            pr.z = fmaf(e, F.z, pr.z);                                   \
            pr.w = fmaf(e, F.w, pr.w);                                   \
            zr += e;                                                     \
        }

    for (int i = 0; i < 8; ++i) {
        const float4 f0 = *reinterpret_cast<const float4*>(fb + 0 * 16 * CT);
        const float4 f1 = *reinterpret_cast<const float4*>(fb + 1 * 16 * CT);
        const float4 f2 = *reinterpret_cast<const float4*>(fb + 2 * 16 * CT);
        const float4 f3 = *reinterpret_cast<const float4*>(fb + 3 * 16 * CT);
        fb += istr;

        float4 pr = make_float4(0,0,0,0);
        float zr = 0.f;
        STEP(f0, cr0, zc0)
        STEP(f1, cr1, zc1)
        STEP(f2, cr2, zc2)
        STEP(f3, cr3, zc3)

        // reduce row contribution over the wave's 4 u-lanes
        pr.x += __shfl_xor(pr.x, 16); pr.x += __shfl_xor(pr.x, 32);
        pr.y += __shfl_xor(pr.y, 16); pr.y += __shfl_xor(pr.y, 32);
        pr.z += __shfl_xor(pr.z, 16); pr.z += __shfl_xor(pr.z, 32);
        pr.w += __shfl_xor(pr.w, 16); pr.w += __shfl_xor(pr.w, 32);
        zr   += __shfl_xor(zr, 16);   zr   += __shfl_xor(zr, 32);

        if ((t & 48) == 0) {
            float4* dst = reinterpret_cast<float4*>(&rpart[w][i][q * 4]);
            float4 v = *dst;
            v.x += pr.x; v.y += pr.y; v.z += pr.z; v.w += pr.w;
            *dst = v;
            if (q == 0) rpart[w][i][64] += zr;
        }
    }
    #undef STEP
    __syncthreads();

    // fold row partials over 4 waves -> rp[bj][i0+ii][*]
    if (t < 128) {
        int ii = t >> 4, c4 = t & 15;
        float4 a  = *reinterpret_cast<const float4*>(&rpart[0][ii][c4 * 4]);
        const float4 b1 = *reinterpret_cast<const float4*>(&rpart[1][ii][c4 * 4]);
        const float4 b2 = *reinterpret_cast<const float4*>(&rpart[2][ii][c4 * 4]);
        const float4 b3 = *reinterpret_cast<const float4*>(&rpart[3][ii][c4 * 4]);
        a.x += b1.x + b2.x + b3.x;
        a.y += b1.y + b2.y + b3.y;
        a.z += b1.z + b2.z + b3.z;
        a.w += b1.w + b2.w + b3.w;
        *reinterpret_cast<float4*>(rp + ((size_t)bj * LL + i0 + ii) * PCH + c4 * 4) = a;
    }
    if (t < 8) {
        float zz = rpart[0][t][64] + rpart[1][t][64] + rpart[2][t][64] + rpart[3][t][64];
        rp[((size_t)bj * LL + i0 + t) * PCH + 64] = zz;
    }

    // col partials out (registers -> global)
    {
        size_t cb = ((size_t)bi * LL + j0 + u) * PCH + q * 4;
        const size_t cstr = (size_t)16 * PCH;
        *reinterpret_cast<float4*>(cp + cb + 0 * cstr) = cr0;
        *reinterpret_cast<float4*>(cp + cb + 1 * cstr) = cr1;
        *reinterpret_cast<float4*>(cp + cb + 2 * cstr) = cr2;
        *reinterpret_cast<float4*>(cp + cb + 3 * cstr) = cr3;
        if (q == 0) {
            size_t zb = ((size_t)bi * LL + j0 + u) * PCH + 64;
            cp[zb + 0 * cstr] = zc0;
            cp[zb + 1 * cstr] = zc1;
            cp[zb + 2 * cstr] = zc2;
            cp[zb + 3 * cstr] = zc3;
        }
    }
}

// ---------------- K2: fold strip-partials, divide by z -> rcfeat ----------
__global__ __launch_bounds__(256) void k_combine(const float* __restrict__ rp,
                                                 const float* __restrict__ cp,
                                                 float* __restrict__ rcfeat) {
    int t = threadIdx.x;
    int r = t >> 4, q = t & 15;
    int L0 = blockIdx.x * 16;
    int side = blockIdx.y;
    const float* base = side ? cp : rp;
    int n = side ? NIS : NJS;

    float4 acc = make_float4(0.f, 0.f, 0.f, 0.f);
    float z = 0.f;
    for (int s = 0; s < n; ++s) {
        const float* p = base + ((size_t)s * LL + L0 + r) * PCH;
        const float4 v = *reinterpret_cast<const float4*>(p + q * 4);
        acc.x += v.x; acc.y += v.y; acc.z += v.z; acc.w += v.w;
        z += p[64];
    }
    float inv = 1.0f / z;
    acc.x *= inv; acc.y *= inv; acc.z *= inv; acc.w *= inv;
    *reinterpret_cast<float4*>(rcfeat + (size_t)side * LL * CT
                               + (L0 + r) * CT + q * 4) = acc;
}

// ---------------- K3: diag gather + LN + (x @ W + b) [*sigma] ----------------
__global__ __launch_bounds__(256) void k_final(const float* __restrict__ feat,
                                               const float* __restrict__ rcfeat,
                                               const float* __restrict__ ln_g,
                                               const float* __restrict__ ln_b,
                                               const float* __restrict__ WU,
                                               const float* __restrict__ bU,
                                               const float* __restrict__ WV,
                                               const float* __restrict__ bV,
                                               const float* __restrict__ sigma,
                                               float* __restrict__ out) {
    __shared__ float xbuf[8][KD];
    int t = threadIdx.x;
    int wid = t >> 6, l = t & 63;
    int r0 = blockIdx.x * 8;
    int right = blockIdx.y;
    const float* rfeat = rcfeat;
    const float* cfeat = rcfeat + LL * CT;

    for (int r = wid; r < 8; r += 4) {
        int i = r0 + r;
        float d  = feat[((size_t)i * LL + i) * CT + l];
        float rv = rfeat[i * CT + l];
        float cv = cfeat[i * CT + l];
        float sum = d + rv + cv;
        #pragma unroll
        for (int o = 32; o; o >>= 1) sum += __shfl_xor(sum, o);
        float mu = sum * (1.0f / 192.0f);
        float d0 = d - mu, d1 = rv - mu, d2 = cv - mu;
        float sq = d0 * d0 + d1 * d1 + d2 * d2;
        #pragma unroll
        for (int o = 32; o; o >>= 1) sq += __shfl_xor(sq, o);
        float rstd = rsqrtf(sq * (1.0f / 192.0f) + 1e-5f);
        float h0 = d0 * rstd, h1 = d1 * rstd, h2 = d2 * rstd;
        float a1 = right ? h2 : h1;
        float a2 = right ? h1 : h2;
        xbuf[r][l]       = h0 * ln_g[l]       + ln_b[l];
        xbuf[r][64 + l]  = a1 * ln_g[64 + l]  + ln_b[64 + l];
        xbuf[r][128 + l] = a2 * ln_g[128 + l] + ln_b[128 + l];
    }
    __syncthreads();

    const float* W    = right ? WV : WU;
    const float* bias = right ? bV : bU;
    int o = t * 4;
    float4 acc[8];
    #pragma unroll
    for (int r = 0; r < 8; ++r) acc[r] = make_float4(0.f, 0.f, 0.f, 0.f);

    for (int k = 0; k < KD; k += 4) {
        float4 xr[8];
        #pragma unroll
        for (int r = 0; r < 8; ++r)
            xr[r] = *reinterpret_cast<const float4*>(&xbuf[r][k]);
        #pragma unroll
        for (int kk = 0; kk < 4; ++kk) {
            float4 w = *reinterpret_cast<const float4*>(W + (size_t)(k + kk) * OC + o);
            #pragma unroll
            for (int r = 0; r < 8; ++r) {
                float xv = (&xr[r].x)[kk];
                acc[r].x = fmaf(xv, w.x, acc[r].x);
                acc[r].y = fmaf(xv, w.y, acc[r].y);
                acc[r].z = fmaf(xv, w.z, acc[r].z);
                acc[r].w = fmaf(xv, w.w, acc[r].w);
            }
        }
    }

    float4 bb = *reinterpret_cast<const float4*>(bias + o);
    float sg = right ? 1.0f : sigma[o >> 7];
    float* obase = out + (right ? (size_t)LL * OC : 0);
    #pragma unroll
    for (int r = 0; r < 8; ++r) {
        float4 v;
        v.x = (acc[r].x + bb.x) * sg;
        v.y = (acc[r].y + bb.y) * sg;
        v.z = (acc[r].z + bb.z) * sg;
        v.w = (acc[r].w + bb.w) * sg;
        *reinterpret_cast<float4*>(obase + (size_t)(r0 + r) * OC + o) = v;
    }
}

extern "C" void kernel_launch(void* const* d_in, const int* in_sizes, int n_in,
                              void* d_out, int out_size, void* d_ws, size_t ws_size,
                              hipStream_t stream) {
    const float* feat  = (const float*)d_in[0];
    const float* Wq    = (const float*)d_in[1];
    const float* bq    = (const float*)d_in[2];
    const float* ln_g  = (const float*)d_in[3];
    const float* ln_b  = (const float*)d_in[4];
    const float* WU    = (const float*)d_in[5];
    const float* bU    = (const float*)d_in[6];
    const float* WV    = (const float*)d_in[7];
    const float* bV    = (const float*)d_in[8];
    const float* sigma = (const float*)d_in[9];
    float* out = (float*)d_out;

    float* ws     = (float*)d_ws;
    float* rp     = ws;                                   // NJS*LL*PCH
    float* cp     = rp + (size_t)NJS * LL * PCH;          // NIS*LL*PCH
    float* rcfeat = cp + (size_t)NIS * LL * PCH;          // 2*LL*CT

    hipLaunchKernelGGL(k_fused, dim3(NIS * NJS), dim3(256), 0, stream,
                       feat, Wq, bq, rp, cp);
    hipLaunchKernelGGL(k_combine, dim3(LL / 16, 2), dim3(256), 0, stream,
                       rp, cp, rcfeat);
    hipLaunchKernelGGL(k_final, dim3(LL / 8, 2), dim3(256), 0, stream,
                       feat, rcfeat, ln_g, ln_b, WU, bU, WV, bV, sigma, out);
}